// Round 2
// baseline (623.232 us; speedup 1.0000x reference)
//
#include <hip/hip_runtime.h>
#include <cstdint>
#include <type_traits>

// ---------------------------------------------------------------------------
// JanusCrossAttention: B=2,S=2048, Q_DIM=KV_DIM=2048, H=16, D=128, KVH=4
// I/O is fp32 (reference dtype). Internals: bf16 MFMA, fp32 accumulate.
// Pipeline:
//   1. transpose+cast weights -> bf16 [N][K] (BT layout for MFMA B-operand)
//   2. xq = q_stream @ wq ; xk/xv = kv_stream @ wk/wv   (A fp32->bf16 staged)
//   3. per-head RMSNorm on xq,xk (in-place, bf16)
//   4. xv -> V^T layout [b][kvh][d][s]
//   5. flash attention (BQ=64, online softmax) -> attn_out (bf16)
//   6. d_out = attn_out @ wo   (fp32 output)
// ---------------------------------------------------------------------------

using bf16 = __bf16;
using bf16x8 = __attribute__((ext_vector_type(8))) __bf16;
using f32x4  = __attribute__((ext_vector_type(4))) float;

#define SEQ 2048
#define NH 16
#define NKVH 4
#define HD 128

// ---------------------------------------------------------------------------
// 2D transpose + cast: in fp32 [R][C] row-major -> out bf16 [C][R] row-major
__global__ void transpose2d(const float* __restrict__ in, bf16* __restrict__ out,
                            int R, int C) {
    __shared__ bf16 tile[32][33];
    int x  = blockIdx.x * 32 + threadIdx.x;   // col in input
    int y0 = blockIdx.y * 32 + threadIdx.y;
#pragma unroll
    for (int i = 0; i < 32; i += 8) {
        int y = y0 + i;
        if (y < R && x < C) tile[threadIdx.y + i][threadIdx.x] = (bf16)in[(long)y * C + x];
    }
    __syncthreads();
    int ox  = blockIdx.y * 32 + threadIdx.x;  // col in output (= input row)
    int oy0 = blockIdx.x * 32 + threadIdx.y;
#pragma unroll
    for (int i = 0; i < 32; i += 8) {
        int oy = oy0 + i;
        if (oy < C && ox < R) out[(long)oy * R + ox] = tile[threadIdx.x][threadIdx.y + i];
    }
}

// xv natural [b][s][kvh][d] (=[4096][512]) -> vt [b][kvh][d][s], bf16->bf16
__global__ void transpose_v(const bf16* __restrict__ xv, bf16* __restrict__ vt) {
    __shared__ bf16 tile[32][33];
    int z = blockIdx.z; int b = z >> 2, kvh = z & 3;
    int d0 = blockIdx.x * 32, s0 = blockIdx.y * 32;
    const bf16* src = xv + (long)b * SEQ * (NKVH * HD) + kvh * HD;
    int d = d0 + threadIdx.x;
#pragma unroll
    for (int i = 0; i < 32; i += 8) {
        int s = s0 + threadIdx.y + i;
        tile[threadIdx.y + i][threadIdx.x] = src[(long)s * (NKVH * HD) + d];
    }
    __syncthreads();
    bf16* dst = vt + (long)(b * NKVH + kvh) * HD * SEQ;
    int s = s0 + threadIdx.x;
#pragma unroll
    for (int i = 0; i < 32; i += 8) {
        int dd = d0 + threadIdx.y + i;
        dst[(long)dd * SEQ + s] = tile[threadIdx.x][threadIdx.y + i];
    }
}

// ---------------------------------------------------------------------------
// GEMM: C[M][N] = A[M][K] @ BT[N][K]^T. A is fp32 or bf16 (cast during LDS
// staging), BT bf16, C fp32 or bf16. fp32 accumulate.
// 128x128 tile, BK=32, 256 threads (4 waves), 4x4 16x16x32 MFMA per wave.
template <typename AT, typename CT>
__global__ __launch_bounds__(256) void gemm_bt(const AT* __restrict__ A,
                                               const bf16* __restrict__ BT,
                                               CT* __restrict__ C,
                                               int M, int N, int K) {
    __shared__ bf16 As[128][32];
    __shared__ bf16 Bs[128][32];
    const int tid  = threadIdx.x;
    const int wave = tid >> 6, lane = tid & 63;
    const int m0 = blockIdx.y * 128, n0 = blockIdx.x * 128;
    const int wm = (wave >> 1) * 64, wn = (wave & 1) * 64;
    const int lrow = lane & 15, quad = lane >> 4;
    const int lko = quad * 8;

    f32x4 acc[4][4] = {};

    for (int k0 = 0; k0 < K; k0 += 32) {
        // stage A,B tiles: 512 chunks of 8 bf16 each, 2 per thread per matrix
#pragma unroll
        for (int p = 0; p < 2; ++p) {
            int c = p * 256 + tid;
            int row = c >> 2, kc = (c & 3) * 8;
            if constexpr (std::is_same_v<AT, float>) {
                const float* src = &A[(long)(m0 + row) * K + k0 + kc];
                float4 f0 = *(const float4*)(src);
                float4 f1 = *(const float4*)(src + 4);
                bf16 tmp[8] = {(bf16)f0.x, (bf16)f0.y, (bf16)f0.z, (bf16)f0.w,
                               (bf16)f1.x, (bf16)f1.y, (bf16)f1.z, (bf16)f1.w};
                *(uint4*)(&As[row][kc]) = *(const uint4*)(tmp);
            } else {
                *(uint4*)(&As[row][kc]) = *(const uint4*)(&A[(long)(m0 + row) * K + k0 + kc]);
            }
            *(uint4*)(&Bs[row][kc]) = *(const uint4*)(&BT[(long)(n0 + row) * K + k0 + kc]);
        }
        __syncthreads();
        bf16x8 af[4], bfr[4];
#pragma unroll
        for (int i = 0; i < 4; ++i) af[i]  = *(const bf16x8*)(&As[wm + i * 16 + lrow][lko]);
#pragma unroll
        for (int j = 0; j < 4; ++j) bfr[j] = *(const bf16x8*)(&Bs[wn + j * 16 + lrow][lko]);
#pragma unroll
        for (int i = 0; i < 4; ++i)
#pragma unroll
            for (int j = 0; j < 4; ++j)
                acc[i][j] = __builtin_amdgcn_mfma_f32_16x16x32_bf16(af[i], bfr[j], acc[i][j], 0, 0, 0);
        __syncthreads();
    }
    // epilogue: C/D layout col=lane&15, row=quad*4+reg
#pragma unroll
    for (int i = 0; i < 4; ++i) {
        int mrow0 = m0 + wm + i * 16 + quad * 4;
#pragma unroll
        for (int j = 0; j < 4; ++j) {
            int ncol = n0 + wn + j * 16 + lrow;
#pragma unroll
            for (int r = 0; r < 4; ++r)
                C[(long)(mrow0 + r) * N + ncol] = (CT)acc[i][j][r];
        }
    }
}

// ---------------------------------------------------------------------------
// Per-head RMSNorm, wave per 128-vector, in-place safe. Gamma is fp32.
__global__ __launch_bounds__(256) void rmsnorm_head(const bf16* __restrict__ X,
                                                    const float* __restrict__ W,
                                                    bf16* __restrict__ Y, int nvec) {
    int v = blockIdx.x * 4 + (threadIdx.x >> 6);
    int lane = threadIdx.x & 63;
    if (v >= nvec) return;
    const bf16* x = X + (long)v * HD;
    float fa = (float)x[lane * 2], fb = (float)x[lane * 2 + 1];
    float ss = fa * fa + fb * fb;
#pragma unroll
    for (int off = 1; off < 64; off <<= 1) ss += __shfl_xor(ss, off, 64);
    float r = rsqrtf(ss * (1.0f / 128.0f) + 1e-5f);
    bf16* y = Y + (long)v * HD;
    y[lane * 2]     = (bf16)(fa * r * W[lane * 2]);
    y[lane * 2 + 1] = (bf16)(fb * r * W[lane * 2 + 1]);
}

// ---------------------------------------------------------------------------
// Flash attention. Grid: (S/64, H, B). Block 256 = 4 waves, wave owns 16 q rows.
// Q: [b][s][h*128+d] (stride 2048), K: [b][s][kvh*128+d] (stride 512),
// VT: [b][kvh][d][s], O: [b][s][h*128+d]   (all bf16)
__global__ __launch_bounds__(256) void attn_kernel(const bf16* __restrict__ Q,
                                                   const bf16* __restrict__ Kn,
                                                   const bf16* __restrict__ VT,
                                                   bf16* __restrict__ O) {
    __shared__ bf16 Qs[64][136];       // +8 pad: breaks 256B-stride bank aliasing
    __shared__ bf16 Ks[64][136];
    __shared__ bf16 Vs[128][72];
    __shared__ bf16 Ps[4][16][72];
    const int tid = threadIdx.x, wave = tid >> 6, lane = tid & 63;
    const int q0 = blockIdx.x * 64;
    const int h = blockIdx.y, b = blockIdx.z;
    const int kvh = h >> 2;
    const int lrow = lane & 15, quad = lane >> 4;
    const float scale = 0.08838834764831845f;  // 1/sqrt(128)

    // stage Q tile (64 x 128)
    {
        const bf16* qbase = Q + ((long)(b * SEQ + q0)) * (NH * HD) + h * HD;
#pragma unroll
        for (int p = 0; p < 4; ++p) {
            int c = p * 256 + tid;
            int r = c >> 4, dc = (c & 15) * 8;
            *(uint4*)(&Qs[r][dc]) = *(const uint4*)(qbase + (long)r * (NH * HD) + dc);
        }
    }
    __syncthreads();
    bf16x8 aq[4];
#pragma unroll
    for (int ks = 0; ks < 4; ++ks)
        aq[ks] = *(const bf16x8*)(&Qs[wave * 16 + lrow][ks * 32 + quad * 8]);

    float m_i[4], l_i[4];
    f32x4 o_acc[8] = {};
#pragma unroll
    for (int r = 0; r < 4; ++r) { m_i[r] = -__builtin_inff(); l_i[r] = 0.f; }

    const bf16* kbase = Kn + (long)b * SEQ * (NKVH * HD) + kvh * HD;  // row stride 512
    const bf16* vbase = VT + (long)(b * NKVH + kvh) * HD * SEQ;       // row stride 2048

    const int nkb = blockIdx.x + 1;
    for (int kb = 0; kb < nkb; ++kb) {
        // stage K (64 x 128) and V^T (128 x 64)
#pragma unroll
        for (int p = 0; p < 4; ++p) {
            int c = p * 256 + tid;
            int r = c >> 4, dc = (c & 15) * 8;
            *(uint4*)(&Ks[r][dc]) = *(const uint4*)(kbase + (long)(kb * 64 + r) * (NKVH * HD) + dc);
        }
#pragma unroll
        for (int p = 0; p < 4; ++p) {
            int c = p * 256 + tid;
            int r = c >> 3, sc = (c & 7) * 8;
            *(uint4*)(&Vs[r][sc]) = *(const uint4*)(vbase + (long)r * SEQ + kb * 64 + sc);
        }
        __syncthreads();

        // scores: 16 q rows x 64 k cols
        float sc4[4][4];  // [nt][reg]
#pragma unroll
        for (int nt = 0; nt < 4; ++nt) {
            f32x4 acc = {};
#pragma unroll
            for (int ks = 0; ks < 4; ++ks) {
                bf16x8 bk = *(const bf16x8*)(&Ks[nt * 16 + lrow][ks * 32 + quad * 8]);
                acc = __builtin_amdgcn_mfma_f32_16x16x32_bf16(aq[ks], bk, acc, 0, 0, 0);
            }
            int kpos = kb * 64 + nt * 16 + lrow;
#pragma unroll
            for (int r = 0; r < 4; ++r) {
                int qpos = q0 + wave * 16 + quad * 4 + r;
                float v = acc[r] * scale;
                sc4[nt][r] = (kpos <= qpos) ? v : -__builtin_inff();
            }
        }
        // online softmax (row stats live in the 16-lane quad)
        float alpha[4];
#pragma unroll
        for (int r = 0; r < 4; ++r) {
            float mx = fmaxf(fmaxf(sc4[0][r], sc4[1][r]), fmaxf(sc4[2][r], sc4[3][r]));
#pragma unroll
            for (int off = 1; off < 16; off <<= 1) mx = fmaxf(mx, __shfl_xor(mx, off, 64));
            float mnew = fmaxf(m_i[r], mx);
            alpha[r] = __expf(m_i[r] - mnew);
            float rs = 0.f;
#pragma unroll
            for (int nt = 0; nt < 4; ++nt) {
                float p = __expf(sc4[nt][r] - mnew);
                sc4[nt][r] = p;
                rs += p;
            }
#pragma unroll
            for (int off = 1; off < 16; off <<= 1) rs += __shfl_xor(rs, off, 64);
            l_i[r] = l_i[r] * alpha[r] + rs;
            m_i[r] = mnew;
        }
#pragma unroll
        for (int dt = 0; dt < 8; ++dt)
#pragma unroll
            for (int r = 0; r < 4; ++r) o_acc[dt][r] *= alpha[r];

        // P tile to LDS (C-layout -> A-layout transform)
#pragma unroll
        for (int nt = 0; nt < 4; ++nt)
#pragma unroll
            for (int r = 0; r < 4; ++r)
                Ps[wave][quad * 4 + r][nt * 16 + lrow] = (bf16)sc4[nt][r];
        __syncthreads();

        // PV: out[16 q][128 d]
#pragma unroll
        for (int ks2 = 0; ks2 < 2; ++ks2) {
            bf16x8 ap = *(const bf16x8*)(&Ps[wave][lrow][ks2 * 32 + quad * 8]);
#pragma unroll
            for (int dt = 0; dt < 8; ++dt) {
                bf16x8 bv = *(const bf16x8*)(&Vs[dt * 16 + lrow][ks2 * 32 + quad * 8]);
                o_acc[dt] = __builtin_amdgcn_mfma_f32_16x16x32_bf16(ap, bv, o_acc[dt], 0, 0, 0);
            }
        }
        __syncthreads();  // protect Ks/Vs/Ps before next stage
    }

    // epilogue
#pragma unroll
    for (int dt = 0; dt < 8; ++dt) {
#pragma unroll
        for (int r = 0; r < 4; ++r) {
            int q = q0 + wave * 16 + quad * 4 + r;
            O[((long)(b * SEQ + q)) * (NH * HD) + h * HD + dt * 16 + lrow] =
                (bf16)(o_acc[dt][r] / l_i[r]);
        }
    }
}

// ---------------------------------------------------------------------------
extern "C" void kernel_launch(void* const* d_in, const int* in_sizes, int n_in,
                              void* d_out, int out_size, void* d_ws, size_t ws_size,
                              hipStream_t stream) {
    const float* q_stream  = (const float*)d_in[0];
    const float* kv_stream = (const float*)d_in[1];
    const float* wq  = (const float*)d_in[2];
    const float* wk  = (const float*)d_in[3];
    const float* wv  = (const float*)d_in[4];
    const float* wo  = (const float*)d_in[5];
    const float* qnw = (const float*)d_in[6];
    const float* knw = (const float*)d_in[7];
    float* out = (float*)d_out;

    // workspace layout (bf16 elems); total 32M elems = 64 MB
    bf16* ws  = (bf16*)d_ws;
    bf16* wqT = ws;                   // 2048*2048
    bf16* wkT = wqT + 2048L * 2048;   //  512*2048
    bf16* wvT = wkT + 512L * 2048;    //  512*2048
    bf16* woT = wvT + 512L * 2048;    // 2048*2048
    bf16* xq  = woT + 2048L * 2048;   // 4096*2048
    bf16* xk  = xq  + 4096L * 2048;   // 4096*512
    bf16* xv  = xk  + 4096L * 512;    // 4096*512
    bf16* vt  = xv  + 4096L * 512;    // 4096*512
    bf16* ao  = vt  + 4096L * 512;    // 4096*2048

    dim3 tb(32, 8);
    // 1. weight transposes -> bf16 [N][K]
    transpose2d<<<dim3(64, 64), tb, 0, stream>>>(wq, wqT, 2048, 2048);
    transpose2d<<<dim3(16, 64), tb, 0, stream>>>(wk, wkT, 2048, 512);
    transpose2d<<<dim3(16, 64), tb, 0, stream>>>(wv, wvT, 2048, 512);
    transpose2d<<<dim3(64, 64), tb, 0, stream>>>(wo, woT, 2048, 2048);
    // 2. projections (A fp32 -> bf16 staged in LDS)
    gemm_bt<float, bf16><<<dim3(16, 32), 256, 0, stream>>>(q_stream,  wqT, xq, 4096, 2048, 2048);
    gemm_bt<float, bf16><<<dim3(4, 32),  256, 0, stream>>>(kv_stream, wkT, xk, 4096, 512, 2048);
    gemm_bt<float, bf16><<<dim3(4, 32),  256, 0, stream>>>(kv_stream, wvT, xv, 4096, 512, 2048);
    // 3. per-head RMSNorm (in-place)
    rmsnorm_head<<<(4096 * 16) / 4, 256, 0, stream>>>(xq, qnw, xq, 4096 * 16);
    rmsnorm_head<<<(4096 * 4) / 4, 256, 0, stream>>>(xk, knw, xk, 4096 * 4);
    // 4. V -> V^T layout
    transpose_v<<<dim3(4, 64, 8), tb, 0, stream>>>(xv, vt);
    // 5. flash attention
    attn_kernel<<<dim3(32, 16, 2), 256, 0, stream>>>(xq, xk, vt, ao);
    // 6. output projection (fp32 out)
    gemm_bt<bf16, float><<<dim3(16, 32), 256, 0, stream>>>(ao, woT, out, 4096, 2048, 2048);

    (void)in_sizes; (void)n_in; (void)out_size; (void)ws_size;
}

// Round 3
// 473.620 us; speedup vs baseline: 1.3159x; 1.3159x over previous
//
#include <hip/hip_runtime.h>
#include <cstdint>

// ---------------------------------------------------------------------------
// JanusCrossAttention: B=2,S=2048, Q_DIM=KV_DIM=2048, H=16, D=128, KVH=4
// I/O fp32; internals bf16 MFMA, fp32 accumulate.
//   1. cvt q_stream -> bf16 sb ; transpose weights -> bf16 [N][K]
//   2. xq = sb @ wqT  (m97-style global_load_lds GEMM)
//   3. cvt kv_stream -> sb ; xkv = sb @ wkvT  (fused K|V, N=1024)
//   4. per-head RMSNorm xq, xk
//   5. V -> V^T layout [b][kvh][d][s]
//   6. flash attention (paired q-tiles for balance, 3 blocks/CU) -> ao(=sb)
//   7. out = ao @ woT (fp32 out)
// ---------------------------------------------------------------------------

using bf16 = __bf16;
using bf16x8 = __attribute__((ext_vector_type(8))) __bf16;
using f32x4  = __attribute__((ext_vector_type(4))) float;

#define SEQ 2048
#define NH 16
#define NKVH 4
#define HD 128

// async global->LDS, 16B per lane. LDS dest must be wave-uniform base + lane*16.
__device__ __forceinline__ void load_lds16(const bf16* g, bf16* l) {
    __builtin_amdgcn_global_load_lds(
        (const __attribute__((address_space(1))) unsigned int*)g,
        (__attribute__((address_space(3))) unsigned int*)l, 16, 0, 0);
}

// DPP cross-lane (16-lane row) reductions — VALU pipe, not LDS pipe.
template <int CTRL>
__device__ __forceinline__ float dpp_f(float x) {
    return __builtin_bit_cast(float,
        __builtin_amdgcn_update_dpp(0, __builtin_bit_cast(int, x), CTRL, 0xf, 0xf, true));
}
__device__ __forceinline__ float row16_max(float x) {
    x = fmaxf(x, dpp_f<0x128>(x));  // row_ror:8
    x = fmaxf(x, dpp_f<0x124>(x));  // row_ror:4
    x = fmaxf(x, dpp_f<0x122>(x));  // row_ror:2
    x = fmaxf(x, dpp_f<0x121>(x));  // row_ror:1
    return x;
}
__device__ __forceinline__ float row16_sum(float x) {
    x += dpp_f<0x128>(x);
    x += dpp_f<0x124>(x);
    x += dpp_f<0x122>(x);
    x += dpp_f<0x121>(x);
    return x;
}

// ---------------------------------------------------------------------------
__global__ __launch_bounds__(256) void cvt_f32_bf16(const float* __restrict__ in,
                                                    bf16* __restrict__ out, int n8) {
    int i = blockIdx.x * 256 + threadIdx.x;
    if (i >= n8) return;
    const float4* p = (const float4*)in + (long)i * 2;
    float4 f0 = p[0], f1 = p[1];
    bf16x8 o = {(bf16)f0.x, (bf16)f0.y, (bf16)f0.z, (bf16)f0.w,
                (bf16)f1.x, (bf16)f1.y, (bf16)f1.z, (bf16)f1.w};
    *((bf16x8*)out + i) = o;
}

// 2D transpose + cast: in fp32 [R][C] -> out bf16 [C][R]
__global__ void transpose2d(const float* __restrict__ in, bf16* __restrict__ out,
                            int R, int C) {
    __shared__ bf16 tile[32][33];
    int x  = blockIdx.x * 32 + threadIdx.x;
    int y0 = blockIdx.y * 32 + threadIdx.y;
#pragma unroll
    for (int i = 0; i < 32; i += 8) {
        int y = y0 + i;
        if (y < R && x < C) tile[threadIdx.y + i][threadIdx.x] = (bf16)in[(long)y * C + x];
    }
    __syncthreads();
    int ox  = blockIdx.y * 32 + threadIdx.x;
    int oy0 = blockIdx.x * 32 + threadIdx.y;
#pragma unroll
    for (int i = 0; i < 32; i += 8) {
        int oy = oy0 + i;
        if (oy < C && ox < R) out[(long)oy * R + ox] = tile[threadIdx.x][threadIdx.y + i];
    }
}

// xv part of xkv [b][s][512 + kvh*128 + d] (row stride given) -> vt [b][kvh][d][s]
__global__ void transpose_v(const bf16* __restrict__ xv, bf16* __restrict__ vt,
                            int stride) {
    __shared__ bf16 tile[32][33];
    int z = blockIdx.z; int b = z >> 2, kvh = z & 3;
    int d0 = blockIdx.x * 32, s0 = blockIdx.y * 32;
    const bf16* src = xv + (long)b * SEQ * stride + kvh * HD;
    int d = d0 + threadIdx.x;
#pragma unroll
    for (int i = 0; i < 32; i += 8) {
        int s = s0 + threadIdx.y + i;
        tile[threadIdx.y + i][threadIdx.x] = src[(long)s * stride + d];
    }
    __syncthreads();
    bf16* dst = vt + (long)(b * NKVH + kvh) * HD * SEQ;
    int s = s0 + threadIdx.x;
#pragma unroll
    for (int i = 0; i < 32; i += 8) {
        int dd = d0 + threadIdx.y + i;
        dst[(long)dd * SEQ + s] = tile[threadIdx.x][threadIdx.y + i];
    }
}

// ---------------------------------------------------------------------------
// GEMM: C[M][N] = A[M][K] @ BT[N][K]^T, bf16 in, fp32 acc, CT out.
// m97 recipe: 128x128 tile, BK=32, global_load_lds width-16 staging.
template <typename CT>
__global__ __launch_bounds__(256) void gemm_bt(const bf16* __restrict__ A,
                                               const bf16* __restrict__ BT,
                                               CT* __restrict__ C,
                                               int M, int N, int K) {
    __shared__ bf16 As[128][32];
    __shared__ bf16 Bs[128][32];
    const int tid  = threadIdx.x;
    const int wave = tid >> 6, lane = tid & 63;
    const int m0 = blockIdx.y * 128, n0 = blockIdx.x * 128;
    const int wm = (wave >> 1) * 64, wn = (wave & 1) * 64;
    const int lrow = lane & 15, quad = lane >> 4;
    const int lko = quad * 8;

    // chunk c = tid (+256): row=c>>2, kcol=(c&3)*8; LDS offset = c*16B (contiguous)
    const bf16* ga0 = A  + (long)(m0 + (tid >> 2)) * K + (tid & 3) * 8;
    const bf16* ga1 = ga0 + 64L * K;
    const bf16* gb0 = BT + (long)(n0 + (tid >> 2)) * K + (tid & 3) * 8;
    const bf16* gb1 = gb0 + 64L * K;
    bf16* la0 = &As[0][0] + tid * 8;
    bf16* la1 = la0 + 2048;
    bf16* lb0 = &Bs[0][0] + tid * 8;
    bf16* lb1 = lb0 + 2048;

    f32x4 acc[4][4] = {};

    for (int k0 = 0; k0 < K; k0 += 32) {
        load_lds16(ga0 + k0, la0);
        load_lds16(ga1 + k0, la1);
        load_lds16(gb0 + k0, lb0);
        load_lds16(gb1 + k0, lb1);
        __syncthreads();   // compiler drains vmcnt(0) before s_barrier
        bf16x8 af[4], bfr[4];
#pragma unroll
        for (int i = 0; i < 4; ++i) af[i]  = *(const bf16x8*)(&As[wm + i * 16 + lrow][lko]);
#pragma unroll
        for (int j = 0; j < 4; ++j) bfr[j] = *(const bf16x8*)(&Bs[wn + j * 16 + lrow][lko]);
#pragma unroll
        for (int i = 0; i < 4; ++i)
#pragma unroll
            for (int j = 0; j < 4; ++j)
                acc[i][j] = __builtin_amdgcn_mfma_f32_16x16x32_bf16(af[i], bfr[j], acc[i][j], 0, 0, 0);
        __syncthreads();
    }
    // C/D layout: col=lane&15, row=quad*4+reg
#pragma unroll
    for (int i = 0; i < 4; ++i) {
        int mrow0 = m0 + wm + i * 16 + quad * 4;
#pragma unroll
        for (int j = 0; j < 4; ++j) {
            int ncol = n0 + wn + j * 16 + lrow;
#pragma unroll
            for (int r = 0; r < 4; ++r)
                C[(long)(mrow0 + r) * N + ncol] = (CT)acc[i][j][r];
        }
    }
}

// ---------------------------------------------------------------------------
// Per-head RMSNorm, wave per 128-vector, in-place. Row stride / heads-per-row
// parameterized (xq: stride 2048, lhpr 4; xk in xkv: stride 1024, lhpr 2).
__global__ __launch_bounds__(256) void rmsnorm_head(bf16* __restrict__ X,
                                                    const float* __restrict__ W,
                                                    int nvec, int lhpr, int stride) {
    int v = blockIdx.x * 4 + (threadIdx.x >> 6);
    int lane = threadIdx.x & 63;
    if (v >= nvec) return;
    int row = v >> lhpr, head = v & ((1 << lhpr) - 1);
    bf16* x = X + (long)row * stride + head * HD;
    float fa = (float)x[lane * 2], fb = (float)x[lane * 2 + 1];
    float ss = fa * fa + fb * fb;
#pragma unroll
    for (int off = 1; off < 64; off <<= 1) ss += __shfl_xor(ss, off, 64);
    float r = rsqrtf(ss * (1.0f / 128.0f) + 1e-5f);
    x[lane * 2]     = (bf16)(fa * r * W[lane * 2]);
    x[lane * 2 + 1] = (bf16)(fb * r * W[lane * 2 + 1]);
}

// ---------------------------------------------------------------------------
// Flash attention, paired q-tiles. Grid: (16 pairs, H, B), block 256 = 4 waves.
// Block p processes q-tiles {31-p, p} sequentially -> uniform 33 k-tiles/block.
// Wave owns 16 q rows; Q frags loaded straight from global (no Qs LDS).
// Q: [b][s][h*128+d] stride 2048; K: xkv [b][s][kvh*128+d] stride kstride;
// VT: [b][kvh][d][s]; O: [b][s][h*128+d]
__global__ __launch_bounds__(256) void attn_kernel(const bf16* __restrict__ Q,
                                                   const bf16* __restrict__ Kn,
                                                   const bf16* __restrict__ VT,
                                                   bf16* __restrict__ O, int kstride) {
    __shared__ bf16 Ks[64][136];   // +8 pad (keeps 16B alignment of rows)
    __shared__ bf16 Vs[128][72];
    __shared__ bf16 Ps[4][16][72];
    const int tid = threadIdx.x, wave = tid >> 6, lane = tid & 63;
    const int pr = blockIdx.x;
    const int h = blockIdx.y, b = blockIdx.z;
    const int kvh = h >> 2;
    const int lrow = lane & 15, quad = lane >> 4;
    const float scale = 0.08838834764831845f;  // 1/sqrt(128)

    const bf16* kbase = Kn + (long)b * SEQ * kstride + kvh * HD;
    const bf16* vbase = VT + (long)(b * NKVH + kvh) * HD * SEQ;  // row stride SEQ

#pragma unroll 1
    for (int t = 0; t < 2; ++t) {
        const int qt = t ? pr : (31 - pr);
        const int q0 = qt * 64;
        const int nkb = qt + 1;

        // Q fragments direct from global: row = q0+wave*16+lrow, col = ks*32+quad*8
        const bf16* qrow = Q + ((long)(b * SEQ + q0 + wave * 16 + lrow)) * (NH * HD) + h * HD;
        bf16x8 aq[4];
#pragma unroll
        for (int ks = 0; ks < 4; ++ks)
            aq[ks] = *(const bf16x8*)(qrow + ks * 32 + quad * 8);

        float m_i[4], l_i[4];
        f32x4 o_acc[8] = {};
#pragma unroll
        for (int r = 0; r < 4; ++r) { m_i[r] = -__builtin_inff(); l_i[r] = 0.f; }

        for (int kb = 0; kb < nkb; ++kb) {
            // stage K (64x128) and V^T (128x64)
#pragma unroll
            for (int p = 0; p < 4; ++p) {
                int c = p * 256 + tid;
                int r = c >> 4, dc = (c & 15) * 8;
                *(uint4*)(&Ks[r][dc]) = *(const uint4*)(kbase + (long)(kb * 64 + r) * kstride + dc);
            }
#pragma unroll
            for (int p = 0; p < 4; ++p) {
                int c = p * 256 + tid;
                int r = c >> 3, sc = (c & 7) * 8;
                *(uint4*)(&Vs[r][sc]) = *(const uint4*)(vbase + (long)r * SEQ + kb * 64 + sc);
            }
            __syncthreads();

            // scores: 16 q rows x 64 k cols
            float sc4[4][4];  // [nt][reg]
            const bool diag = (kb == nkb - 1);
#pragma unroll
            for (int nt = 0; nt < 4; ++nt) {
                f32x4 acc = {};
#pragma unroll
                for (int ks = 0; ks < 4; ++ks) {
                    bf16x8 bk = *(const bf16x8*)(&Ks[nt * 16 + lrow][ks * 32 + quad * 8]);
                    acc = __builtin_amdgcn_mfma_f32_16x16x32_bf16(aq[ks], bk, acc, 0, 0, 0);
                }
                if (diag) {
                    int kpos = kb * 64 + nt * 16 + lrow;
#pragma unroll
                    for (int r = 0; r < 4; ++r) {
                        int qpos = q0 + wave * 16 + quad * 4 + r;
                        sc4[nt][r] = (kpos <= qpos) ? acc[r] * scale : -__builtin_inff();
                    }
                } else {
#pragma unroll
                    for (int r = 0; r < 4; ++r) sc4[nt][r] = acc[r] * scale;
                }
            }
            // online softmax: per-row stats via DPP 16-lane reductions (VALU pipe)
            float alpha[4];
#pragma unroll
            for (int r = 0; r < 4; ++r) {
                float mx = fmaxf(fmaxf(sc4[0][r], sc4[1][r]), fmaxf(sc4[2][r], sc4[3][r]));
                mx = row16_max(mx);
                float mnew = fmaxf(m_i[r], mx);
                alpha[r] = __expf(m_i[r] - mnew);
                float rs = 0.f;
#pragma unroll
                for (int nt = 0; nt < 4; ++nt) {
                    float p = __expf(sc4[nt][r] - mnew);
                    sc4[nt][r] = p;
                    rs += p;
                }
                rs = row16_sum(rs);
                l_i[r] = l_i[r] * alpha[r] + rs;
                m_i[r] = mnew;
            }
#pragma unroll
            for (int dt = 0; dt < 8; ++dt)
#pragma unroll
                for (int r = 0; r < 4; ++r) o_acc[dt][r] *= alpha[r];

            // P tile to LDS (C-layout -> A-layout); wave-private, in-order DS
#pragma unroll
            for (int nt = 0; nt < 4; ++nt)
#pragma unroll
                for (int r = 0; r < 4; ++r)
                    Ps[wave][quad * 4 + r][nt * 16 + lrow] = (bf16)sc4[nt][r];

            // PV: out[16 q][128 d]
#pragma unroll
            for (int ks2 = 0; ks2 < 2; ++ks2) {
                bf16x8 ap = *(const bf16x8*)(&Ps[wave][lrow][ks2 * 32 + quad * 8]);
#pragma unroll
                for (int dt = 0; dt < 8; ++dt) {
                    bf16x8 bv = *(const bf16x8*)(&Vs[dt * 16 + lrow][ks2 * 32 + quad * 8]);
                    o_acc[dt] = __builtin_amdgcn_mfma_f32_16x16x32_bf16(ap, bv, o_acc[dt], 0, 0, 0);
                }
            }
            __syncthreads();  // protect Ks/Vs before next staging
        }

        // epilogue for this q-tile
#pragma unroll
        for (int dt = 0; dt < 8; ++dt) {
#pragma unroll
            for (int r = 0; r < 4; ++r) {
                int q = q0 + wave * 16 + quad * 4 + r;
                O[((long)(b * SEQ + q)) * (NH * HD) + h * HD + dt * 16 + lrow] =
                    (bf16)(o_acc[dt][r] / l_i[r]);
            }
        }
    }
}

// ---------------------------------------------------------------------------
extern "C" void kernel_launch(void* const* d_in, const int* in_sizes, int n_in,
                              void* d_out, int out_size, void* d_ws, size_t ws_size,
                              hipStream_t stream) {
    const float* q_stream  = (const float*)d_in[0];
    const float* kv_stream = (const float*)d_in[1];
    const float* wq  = (const float*)d_in[2];
    const float* wk  = (const float*)d_in[3];
    const float* wv  = (const float*)d_in[4];
    const float* wo  = (const float*)d_in[5];
    const float* qnw = (const float*)d_in[6];
    const float* knw = (const float*)d_in[7];
    float* out = (float*)d_out;

    // workspace (bf16 elems), total 28M elems = 56MB
    bf16* ws   = (bf16*)d_ws;
    bf16* sb   = ws;                        // 8M: stream buf, later attn out
    bf16* wqT  = ws + 8L * 1024 * 1024;     // 4M: wq^T, later wo^T
    bf16* wkvT = wqT + 4L * 1024 * 1024;    // 2M: [wk^T ; wv^T] = [1024][2048]
    bf16* xq   = wkvT + 2L * 1024 * 1024;   // 8M: [4096][2048]
    bf16* xkv  = xq + 8L * 1024 * 1024;     // 4M: [4096][1024] = [K | V]
    bf16* vt   = xkv + 4L * 1024 * 1024;    // 2M: [b][kvh][d][s]

    dim3 tb(32, 8);
    // q_stream -> bf16
    cvt_f32_bf16<<<4096, 256, 0, stream>>>(q_stream, sb, 1048576);
    // weight transposes
    transpose2d<<<dim3(64, 64), tb, 0, stream>>>(wq, wqT, 2048, 2048);
    transpose2d<<<dim3(16, 64), tb, 0, stream>>>(wk, wkvT, 2048, 512);
    transpose2d<<<dim3(16, 64), tb, 0, stream>>>(wv, wkvT + 512L * 2048, 2048, 512);
    // Q projection
    gemm_bt<bf16><<<dim3(16, 32), 256, 0, stream>>>(sb, wqT, xq, 4096, 2048, 2048);
    // kv_stream -> bf16 (sb dead after q-proj)
    cvt_f32_bf16<<<4096, 256, 0, stream>>>(kv_stream, sb, 1048576);
    // wo^T (overwrites wqT — dead after q-proj)
    transpose2d<<<dim3(64, 64), tb, 0, stream>>>(wo, wqT, 2048, 2048);
    // fused K|V projection (N=1024)
    gemm_bt<bf16><<<dim3(8, 32), 256, 0, stream>>>(sb, wkvT, xkv, 4096, 1024, 2048);
    // RMSNorm (in-place)
    rmsnorm_head<<<(4096 * 16) / 4, 256, 0, stream>>>(xq, qnw, 4096 * 16, 4, 2048);
    rmsnorm_head<<<(4096 * 4) / 4, 256, 0, stream>>>(xkv, knw, 4096 * 4, 2, 1024);
    // V -> V^T
    transpose_v<<<dim3(4, 64, 8), tb, 0, stream>>>(xkv + 512, vt, 1024);
    // flash attention (ao aliases sb — kv copy dead)
    attn_kernel<<<dim3(16, 16, 2), 256, 0, stream>>>(xq, xkv, vt, sb, 1024);
    // output projection
    gemm_bt<float><<<dim3(16, 32), 256, 0, stream>>>(sb, wqT, out, 4096, 2048, 2048);

    (void)in_sizes; (void)n_in; (void)out_size; (void)ws_size;
}